// Round 2
// baseline (3768.385 us; speedup 1.0000x reference)
//
#include <hip/hip_runtime.h>

// SNN forward, small-footprint (52.7 MB ws; previous 371 MB version memory-faulted):
//   conv1 stats pass -> bn1 finalize -> fused conv1+BN+LIF+pool (bf16 spikes out)
//   conv2 stats pass -> bn2 finalize -> fused conv2+BN+LIF+pool (bf16 out)
//   fc1 gemm (split-K) -> LIF -> fc2
// All value math fp32 (no fp32 MFMA on CDNA4); bf16 only stores exact values
// (pooled spikes are multiples of 0.25 -> lossless in bf16).

#define LIF_STEP(vv, xx, ss) do { \
    vv = fmaf((xx) - vv, 0.5f, vv); \
    ss = (vv >= 1.0f) ? 1.0f : 0.0f; \
    vv = (vv >= 1.0f) ? 0.0f : vv; \
  } while (0)

__device__ __forceinline__ float bf2f(unsigned short u) {
  return __uint_as_float(((unsigned)u) << 16);
}
__device__ __forceinline__ unsigned short f2bf(float f) {
  return (unsigned short)(__float_as_uint(f) >> 16);  // exact for k/4 values
}

// ---- workspace layout (float-slot offsets) ----
#define OFF_POOL1   0u          // bf16 [8,128,64,16,16] = 16,777,216 bf16 = 8,388,608 f-slots
#define OFF_POOL2   8388608u    // bf16 [8,128,128,8,8]  =  8,388,608 bf16 = 4,194,304 f-slots
#define OFF_FC1OUT  12582912u   // f32 [8,128,256] = 262,144
#define OFF_STATS   12845056u   // f32 768: s1sum(64) s1sq(64) bn1sc(64) bn1sh(64) s2sum(128) s2sq(128) bn2sc(128) bn2sh(128)
#define OFF_FC1S    12845824u   // f32 262,144
#define OFF_WT2     13107968u   // f32 73,728 : conv2 w transposed [9][64][128]
// total 13,181,696 floats = 52.7 MB
#define ZERO_N      262912u     // fc1_out + stats (contiguous), = 1027*256 exactly

__global__ __launch_bounds__(256) void zero_kernel(float* __restrict__ p, unsigned n) {
  unsigned i = blockIdx.x * 256u + threadIdx.x;
  if (i < n) p[i] = 0.0f;
}

// conv2_w [128][64][3][3] -> wt [k=9][ci=64][co=128]
__global__ __launch_bounds__(256) void transpose_w2(const float* __restrict__ w, float* __restrict__ wt) {
  unsigned i = blockIdx.x * 256u + threadIdx.x;
  if (i < 73728u) {
    unsigned co = i / 576u, rem = i - co * 576u;
    unsigned ci = rem / 9u, k = rem - ci * 9u;
    wt[(k * 64u + ci) * 128u + co] = w[i];
  }
}

// ---- conv1 pass 1: stats only (no stores). Block per (t,b) image. ----
__global__ __launch_bounds__(256) void conv1_pass1(const float* __restrict__ x,
                                                   const float* __restrict__ w,
                                                   float* __restrict__ s_sum,
                                                   float* __restrict__ s_sq) {
  int tb = blockIdx.x;
  __shared__ float simg[3 * 32 * 36];  // cols padded: col = global col + 1
  int tid = threadIdx.x;
  const float* xb = x + tb * 3072;
  for (int i = tid; i < 3456; i += 256) {
    int ci = i / 1152, rem = i - ci * 1152;
    int y = rem / 36, px = rem - y * 36;
    int gx = px - 1;
    simg[i] = ((unsigned)gx < 32u) ? xb[(ci * 32 + y) * 32 + gx] : 0.0f;
  }
  __syncthreads();

  int cgrp = tid >> 3, rowthr = tid & 7;
  int c0 = cgrp * 2;
  float w0[27], w1[27];
#pragma unroll
  for (int j = 0; j < 27; ++j) { w0[j] = w[c0 * 27 + j]; w1[j] = w[c0 * 27 + 27 + j]; }

  float s1a = 0.f, s2a = 0.f, s1b = 0.f, s2b = 0.f;
  for (int task = 0; task < 8; ++task) {
    int y = rowthr + (task & 3) * 8;
    int x0 = (task >> 2) * 16;
    float acc0[16] = {0.f,0.f,0.f,0.f,0.f,0.f,0.f,0.f,0.f,0.f,0.f,0.f,0.f,0.f,0.f,0.f};
    float acc1[16] = {0.f,0.f,0.f,0.f,0.f,0.f,0.f,0.f,0.f,0.f,0.f,0.f,0.f,0.f,0.f,0.f};
#pragma unroll
    for (int ci = 0; ci < 3; ++ci) {
#pragma unroll
      for (int dy = 0; dy < 3; ++dy) {
        int yy = y + dy - 1;
        if (yy >= 0 && yy < 32) {
          const float* row = simg + (ci * 32 + yy) * 36 + x0;
          float rr[20];
#pragma unroll
          for (int q = 0; q < 5; ++q) {
            float4 f = *(const float4*)(row + q * 4);
            rr[q*4+0] = f.x; rr[q*4+1] = f.y; rr[q*4+2] = f.z; rr[q*4+3] = f.w;
          }
#pragma unroll
          for (int dx = 0; dx < 3; ++dx) {
            float wa = w0[ci*9 + dy*3 + dx], wb = w1[ci*9 + dy*3 + dx];
#pragma unroll
            for (int xi = 0; xi < 16; ++xi) {
              float v = rr[xi + dx];
              acc0[xi] = fmaf(wa, v, acc0[xi]);
              acc1[xi] = fmaf(wb, v, acc1[xi]);
            }
          }
        }
      }
    }
#pragma unroll
    for (int xi = 0; xi < 16; ++xi) {
      s1a += acc0[xi]; s2a = fmaf(acc0[xi], acc0[xi], s2a);
      s1b += acc1[xi]; s2b = fmaf(acc1[xi], acc1[xi], s2b);
    }
  }
#pragma unroll
  for (int off = 1; off < 8; off <<= 1) {
    s1a += __shfl_xor(s1a, off); s2a += __shfl_xor(s2a, off);
    s1b += __shfl_xor(s1b, off); s2b += __shfl_xor(s2b, off);
  }
  if (rowthr == 0) {
    atomicAdd(&s_sum[c0], s1a);     atomicAdd(&s_sq[c0], s2a);
    atomicAdd(&s_sum[c0 + 1], s1b); atomicAdd(&s_sq[c0 + 1], s2b);
  }
}

__global__ void finalize_bn(const float* __restrict__ sum, const float* __restrict__ sq,
                            const float* __restrict__ g, const float* __restrict__ b,
                            float* __restrict__ scale, float* __restrict__ shift, float inv_n) {
  int c = threadIdx.x;
  float mean = sum[c] * inv_n;
  float var = fmaxf(sq[c] * inv_n - mean * mean, 0.0f);
  float rstd = rsqrtf(var + 1e-5f);
  float sc = g[c] * rstd;
  scale[c] = sc;
  shift[c] = fmaf(-mean, sc, b[c]);
}

// ---- conv1 pass 2: fused conv+BN+LIF+pool, membrane state in registers across T. ----
// Block = (b, cg 0..7); thread = (co_off 0..7 => channel cg*8+co_off, y 0..31 conv row).
__global__ __launch_bounds__(256) void conv1_fused(const float* __restrict__ x,
    const float* __restrict__ w, const float* __restrict__ scale, const float* __restrict__ shift,
    unsigned short* __restrict__ pool1) {
  int b = blockIdx.x >> 3, cg = blockIdx.x & 7;
  int tid = threadIdx.x;
  int co = cg * 8 + (tid >> 5);
  int y = tid & 31;
  __shared__ float simg[3 * 34 * 36];  // [ci][row=gy+1][col=gx+1], zero-padded borders
  float wreg[27];
#pragma unroll
  for (int j = 0; j < 27; ++j) wreg[j] = w[co * 27 + j];
  float sc = scale[co], sh = shift[co];
  float v[32];
#pragma unroll
  for (int i = 0; i < 32; ++i) v[i] = 0.f;

  for (int t = 0; t < 8; ++t) {
    const float* xb = x + (t * 128 + b) * 3072;
    __syncthreads();  // prev-iter reads done before restage
    for (int i = tid; i < 3672; i += 256) {
      int ci = i / 1224, r = i - ci * 1224;
      int yy = r / 36, xx = r - yy * 36;
      int gy = yy - 1, gx = xx - 1;
      simg[i] = ((unsigned)gy < 32u && (unsigned)gx < 32u) ? xb[(ci * 32 + gy) * 32 + gx] : 0.f;
    }
    __syncthreads();
    float acc[32];
#pragma unroll
    for (int i = 0; i < 32; ++i) acc[i] = 0.f;
#pragma unroll
    for (int ci = 0; ci < 3; ++ci) {
#pragma unroll
      for (int dy = 0; dy < 3; ++dy) {
        const float* row = simg + (ci * 34 + y + dy) * 36;
        float rr[36];
#pragma unroll
        for (int q = 0; q < 9; ++q) {
          float4 f = *(const float4*)(row + q * 4);
          rr[q*4+0]=f.x; rr[q*4+1]=f.y; rr[q*4+2]=f.z; rr[q*4+3]=f.w;
        }
#pragma unroll
        for (int dx = 0; dx < 3; ++dx) {
          float wv = wreg[ci * 9 + dy * 3 + dx];
#pragma unroll
          for (int xx2 = 0; xx2 < 32; ++xx2)
            acc[xx2] = fmaf(wv, rr[xx2 + dx], acc[xx2]);
        }
      }
    }
    // BN + LIF + 2x1 horizontal pool
    float hp[16];
#pragma unroll
    for (int px = 0; px < 16; ++px) {
      float s0, s1, xv;
      xv = fmaf(acc[2*px],   sc, sh); LIF_STEP(v[2*px],   xv, s0);
      xv = fmaf(acc[2*px+1], sc, sh); LIF_STEP(v[2*px+1], xv, s1);
      hp[px] = s0 + s1;
    }
    // vertical pool with partner lane y^1 (same wave: lane = tid&63, y = tid&31)
    unsigned short ob[16];
#pragma unroll
    for (int px = 0; px < 16; ++px) {
      float sum = hp[px] + __shfl_xor(hp[px], 1);
      ob[px] = f2bf(0.25f * sum);
    }
    if ((y & 1) == 0) {
      int py = y >> 1;
      unsigned short* dst = pool1 + (((t * 128 + b) * 64 + co) * 256 + py * 16);
      uint4 u0, u1;
      u0.x = ob[0]  | ((unsigned)ob[1]  << 16); u0.y = ob[2]  | ((unsigned)ob[3]  << 16);
      u0.z = ob[4]  | ((unsigned)ob[5]  << 16); u0.w = ob[6]  | ((unsigned)ob[7]  << 16);
      u1.x = ob[8]  | ((unsigned)ob[9]  << 16); u1.y = ob[10] | ((unsigned)ob[11] << 16);
      u1.z = ob[12] | ((unsigned)ob[13] << 16); u1.w = ob[14] | ((unsigned)ob[15] << 16);
      *(uint4*)dst = u0;
      *(uint4*)(dst + 8) = u1;
    }
  }
}

// ---- conv2 pass 1: stats only. Block per ((t,b) image, y-half); bf16 input staged fp32. ----
__global__ __launch_bounds__(256) void conv2_pass1(const unsigned short* __restrict__ in,
                                                   const float* __restrict__ wt,
                                                   float* __restrict__ s_sum, float* __restrict__ s_sq) {
  int bx = blockIdx.x;
  int img = bx >> 1, half = bx & 1;
  __shared__ float simg[64 * 160];   // [ci][10 rows g-1..g+8][16]
  int tid = threadIdx.x;
  const unsigned short* ibase = in + img * 16384;
  int g = half * 8;
#pragma unroll
  for (int i = 0; i < 40; ++i) {
    int idx = tid + 256 * i;
    int ci = idx / 160, rem = idx - ci * 160;
    int lr = rem >> 4, xx0 = rem & 15;
    int gy = g - 1 + lr;
    simg[idx] = ((unsigned)gy < 16u) ? bf2f(ibase[ci * 256 + gy * 16 + xx0]) : 0.0f;
  }
  __syncthreads();

  int pos = tid & 127, coh = tid >> 7;
  int ly = pos >> 4, xx = pos & 15;

  for (int cot = 0; cot < 4; ++cot) {
    int co0 = coh * 64 + cot * 16;
    float acc[16] = {0.f,0.f,0.f,0.f,0.f,0.f,0.f,0.f,0.f,0.f,0.f,0.f,0.f,0.f,0.f,0.f};
#pragma unroll
    for (int dy = 0; dy < 3; ++dy) {
#pragma unroll
      for (int dx = 0; dx < 3; ++dx) {
        int xn = xx + dx - 1;
        bool vx = (unsigned)xn < 16u;
        float vm = vx ? 1.0f : 0.0f;
        const float* sp = simg + (ly + dy) * 16 + (vx ? xn : 0);
        const float* wp = wt + (dy * 3 + dx) * 8192 + co0;
#pragma unroll 4
        for (int ci = 0; ci < 64; ++ci) {
          float vv = sp[ci * 160] * vm;
#pragma unroll
          for (int j = 0; j < 16; ++j)
            acc[j] = fmaf(vv, wp[ci * 128 + j], acc[j]);
        }
      }
    }
#pragma unroll
    for (int j = 0; j < 16; ++j) {
      float val = acc[j];
      float s1 = val, s2 = val * val;
#pragma unroll
      for (int off = 1; off < 64; off <<= 1) { s1 += __shfl_xor(s1, off); s2 += __shfl_xor(s2, off); }
      if ((tid & 63) == 0) { atomicAdd(&s_sum[co0 + j], s1); atomicAdd(&s_sq[co0 + j], s2); }
    }
  }
}

// ---- conv2 pass 2: fused conv+BN+LIF+pool. Block = (b, cog 0..7 => 16 out-ch). ----
// Thread = pixel (y,x) of 16x16; 16 out-channels per thread (wave-uniform weights).
__global__ __launch_bounds__(256) void conv2_fused(const unsigned short* __restrict__ pool1,
    const float* __restrict__ wt, const float* __restrict__ scale, const float* __restrict__ shift,
    unsigned short* __restrict__ pool2) {
  int b = blockIdx.x >> 3, cog = blockIdx.x & 7;
  int co0 = cog * 16;
  int tid = threadIdx.x;
  int y = tid >> 4, x = tid & 15;
  __shared__ unsigned short simgb[64 * 18 * 18];  // bf16, zero-padded borders; 41.5 KB
  float sc[16], sh[16];
#pragma unroll
  for (int j = 0; j < 16; ++j) { sc[j] = scale[co0 + j]; sh[j] = shift[co0 + j]; }
  float v[16];
#pragma unroll
  for (int j = 0; j < 16; ++j) v[j] = 0.f;

  for (int t = 0; t < 8; ++t) {
    __syncthreads();  // prev compute reads done
    for (int i = tid; i < 10368; i += 256) ((unsigned*)simgb)[i] = 0u;
    __syncthreads();
    const unsigned* in_u = (const unsigned*)(pool1 + (t * 128 + b) * 16384);
#pragma unroll
    for (int k = 0; k < 32; ++k) {
      int i = tid + 256 * k;             // uint id: ci*128 + row*8 + xpair
      unsigned u = in_u[i];
      int ci = i >> 7, r = i & 127;
      int row = r >> 3, xp = r & 7;
      int base = (ci * 18 + row + 1) * 18 + 2 * xp + 1;
      simgb[base]     = (unsigned short)(u & 0xffffu);
      simgb[base + 1] = (unsigned short)(u >> 16);
    }
    __syncthreads();
    float acc[16];
#pragma unroll
    for (int j = 0; j < 16; ++j) acc[j] = 0.f;
#pragma unroll 2
    for (int ci = 0; ci < 64; ++ci) {
#pragma unroll
      for (int dy = 0; dy < 3; ++dy) {
#pragma unroll
        for (int dx = 0; dx < 3; ++dx) {
          float vv = bf2f(simgb[(ci * 18 + y + dy) * 18 + x + dx]);
          const float* wp = wt + ((dy * 3 + dx) * 64 + ci) * 128 + co0;  // wave-uniform -> s_load
#pragma unroll
          for (int j = 0; j < 16; ++j)
            acc[j] = fmaf(vv, wp[j], acc[j]);
        }
      }
    }
    // BN + LIF + 2x2 pool (partners: x^1 = lane^1, y^1 = lane^16)
#pragma unroll
    for (int j = 0; j < 16; ++j) {
      float xv = fmaf(acc[j], sc[j], sh[j]);
      float s;
      LIF_STEP(v[j], xv, s);
      float hp = s + __shfl_xor(s, 1);
      float vp = hp + __shfl_xor(hp, 16);
      if (((x | y) & 1) == 0) {
        int py = y >> 1, px = x >> 1;
        pool2[((t * 128 + b) * 128 + co0 + j) * 64 + py * 8 + px] = f2bf(0.25f * vp);
      }
    }
  }
}

// ---- fc1: C[1024,256] = A_bf16[1024,8192] * B[256,8192]^T, split-K=32 atomic. ----
__global__ __launch_bounds__(256) void fc1_gemm(const unsigned short* __restrict__ A,
                                                const float* __restrict__ B,
                                                float* __restrict__ C) {
  __shared__ float As[16][128];
  __shared__ float Bs[16][128];
  int tid = threadIdx.x;
  int tx = tid & 15, ty = tid >> 4;
  int M0 = blockIdx.x * 128;   // 8
  int N0 = blockIdx.y * 128;   // 2
  int K0 = blockIdx.z * 256;   // 32
  float acc[8][8] = {};
  for (int kc = 0; kc < 256; kc += 16) {
#pragma unroll
    for (int i = 0; i < 2; ++i) {
      int task = tid + 256 * i;
      int m = task >> 2, q = task & 3;
      uint2 a2 = *(const uint2*)(A + (M0 + m) * 8192 + K0 + kc + q * 4);
      As[q*4+0][m] = bf2f((unsigned short)(a2.x & 0xffffu));
      As[q*4+1][m] = bf2f((unsigned short)(a2.x >> 16));
      As[q*4+2][m] = bf2f((unsigned short)(a2.y & 0xffffu));
      As[q*4+3][m] = bf2f((unsigned short)(a2.y >> 16));
      float4 b4 = *(const float4*)(B + (N0 + m) * 8192 + K0 + kc + q * 4);
      Bs[q*4+0][m] = b4.x; Bs[q*4+1][m] = b4.y; Bs[q*4+2][m] = b4.z; Bs[q*4+3][m] = b4.w;
    }
    __syncthreads();
#pragma unroll
    for (int kk = 0; kk < 16; ++kk) {
      float4 a0 = *(const float4*)&As[kk][ty * 8];
      float4 a1 = *(const float4*)&As[kk][ty * 8 + 4];
      float4 b0 = *(const float4*)&Bs[kk][tx * 8];
      float4 b1 = *(const float4*)&Bs[kk][tx * 8 + 4];
      float av[8] = {a0.x,a0.y,a0.z,a0.w,a1.x,a1.y,a1.z,a1.w};
      float bv[8] = {b0.x,b0.y,b0.z,b0.w,b1.x,b1.y,b1.z,b1.w};
#pragma unroll
      for (int i = 0; i < 8; ++i)
#pragma unroll
        for (int j = 0; j < 8; ++j)
          acc[i][j] = fmaf(av[i], bv[j], acc[i][j]);
    }
    __syncthreads();
  }
#pragma unroll
  for (int i = 0; i < 8; ++i)
#pragma unroll
    for (int j = 0; j < 8; ++j)
      atomicAdd(&C[(M0 + ty * 8 + i) * 256 + N0 + tx * 8 + j], acc[i][j]);
}

__global__ __launch_bounds__(256) void lif_fc(const float* __restrict__ fin, float* __restrict__ fs) {
  int idx = blockIdx.x * 256 + threadIdx.x;  // 32768 = (b,o)
  float v = 0.f;
#pragma unroll
  for (int t = 0; t < 8; ++t) {
    float xv = fin[t * 32768 + idx], s;
    LIF_STEP(v, xv, s);
    fs[t * 32768 + idx] = s;
  }
}

__global__ __launch_bounds__(256) void fc2_kernel(const float* __restrict__ fs, const float* __restrict__ w,
                                                  const float* __restrict__ bias, float* __restrict__ outp) {
  int tb = blockIdx.x;
  __shared__ float sv[256];
  int tid = threadIdx.x;
  sv[tid] = fs[tb * 256 + tid];
  __syncthreads();
  if (tid < 10) {
    float a = bias[tid];
    const float* wr = w + tid * 256;
#pragma unroll 8
    for (int o = 0; o < 256; ++o) a = fmaf(sv[o], wr[o], a);
    outp[tb * 10 + tid] = a;
  }
}

extern "C" void kernel_launch(void* const* d_in, const int* in_sizes, int n_in,
                              void* d_out, int out_size, void* d_ws, size_t ws_size,
                              hipStream_t stream) {
  (void)in_sizes; (void)n_in; (void)out_size; (void)ws_size;
  const float* x_seq   = (const float*)d_in[0];
  const float* conv1_w = (const float*)d_in[1];
  const float* bn1_g   = (const float*)d_in[2];
  const float* bn1_b   = (const float*)d_in[3];
  const float* conv2_w = (const float*)d_in[4];
  const float* bn2_g   = (const float*)d_in[5];
  const float* bn2_b   = (const float*)d_in[6];
  const float* fc1_w   = (const float*)d_in[7];
  const float* fc2_w   = (const float*)d_in[8];
  const float* fc2_b   = (const float*)d_in[9];
  float* out = (float*)d_out;
  float* ws  = (float*)d_ws;

  unsigned short* pool1 = (unsigned short*)(ws + OFF_POOL1);
  unsigned short* pool2 = (unsigned short*)(ws + OFF_POOL2);
  float* fc1_out = ws + OFF_FC1OUT;
  float* fc1_s   = ws + OFF_FC1S;
  float* wt2     = ws + OFF_WT2;
  float* st      = ws + OFF_STATS;
  float* s1_sum = st;        float* s1_sq  = st + 64;
  float* bn1_sc = st + 128;  float* bn1_sh = st + 192;
  float* s2_sum = st + 256;  float* s2_sq  = st + 384;
  float* bn2_sc = st + 512;  float* bn2_sh = st + 640;

  // 1. zero fc1_out + stats (contiguous region; ws is poisoned every call)
  zero_kernel<<<1027, 256, 0, stream>>>(fc1_out, ZERO_N);
  // 2. conv2 weight transpose
  transpose_w2<<<288, 256, 0, stream>>>(conv2_w, wt2);
  // 3. conv1 stats (no stores)
  conv1_pass1<<<1024, 256, 0, stream>>>(x_seq, conv1_w, s1_sum, s1_sq);
  // 4. BN1 finalize (N = 8*128*32*32)
  finalize_bn<<<1, 64, 0, stream>>>(s1_sum, s1_sq, bn1_g, bn1_b, bn1_sc, bn1_sh, 1.0f / 1048576.0f);
  // 5. fused conv1+BN+LIF+pool -> pool1 (bf16)
  conv1_fused<<<1024, 256, 0, stream>>>(x_seq, conv1_w, bn1_sc, bn1_sh, pool1);
  // 6. conv2 stats (no stores)
  conv2_pass1<<<2048, 256, 0, stream>>>(pool1, wt2, s2_sum, s2_sq);
  // 7. BN2 finalize (N = 8*128*16*16)
  finalize_bn<<<1, 128, 0, stream>>>(s2_sum, s2_sq, bn2_g, bn2_b, bn2_sc, bn2_sh, 1.0f / 262144.0f);
  // 8. fused conv2+BN+LIF+pool -> pool2 (bf16)
  conv2_fused<<<1024, 256, 0, stream>>>(pool1, wt2, bn2_sc, bn2_sh, pool2);
  // 9. fc1 GEMM (split-K atomics into zeroed fc1_out)
  fc1_gemm<<<dim3(8, 2, 32), 256, 0, stream>>>(pool2, fc1_w, fc1_out);
  // 10. LIF over fc1
  lif_fc<<<128, 256, 0, stream>>>(fc1_out, fc1_s);
  // 11. fc2 + bias -> logits [8,128,10]
  fc2_kernel<<<1024, 256, 0, stream>>>(fc1_s, fc2_w, fc2_b, out);
}

// Round 3
// 994.863 us; speedup vs baseline: 3.7878x; 3.7878x over previous
//
#include <hip/hip_runtime.h>

// SNN forward. conv2 (the 19.3-GMAC dominant op) now runs on MFMA bf16 with a
// 3-way weight split (hi+lo+lolo bf16; residual ~2^-24 rel -> fp32-grade).
// Spike inputs are exact in bf16, so products are exact; accumulate is fp32.
//   conv1 stats -> bn1 -> fused conv1+BN+LIF+pool (bf16 spikes, conv2-friendly layout)
//   conv2 stats (MFMA) -> bn2 -> fused conv2+BN+LIF+pool (MFMA, membrane in C-frag regs)
//   fc1 gemm (unchanged, validated) -> LIF -> fc2

#define LIF_STEP(vv, xx, ss) do { \
    vv = fmaf((xx) - vv, 0.5f, vv); \
    ss = (vv >= 1.0f) ? 1.0f : 0.0f; \
    vv = (vv >= 1.0f) ? 0.0f : vv; \
  } while (0)

typedef __attribute__((ext_vector_type(8))) short short8;
typedef __attribute__((ext_vector_type(4))) float f32x4;

__device__ __forceinline__ float bf2f(unsigned short u) {
  return __uint_as_float(((unsigned)u) << 16);
}
__device__ __forceinline__ unsigned short f2bf(float f) {
  return (unsigned short)(__float_as_uint(f) >> 16);  // truncation; exact for k/4 spike values
}

// ---- workspace layout (float-slot offsets) ----
// pool1 bf16 [1024 tb][8 cg][16 py][16 px][8 ci_l]  = 16,777,216 u16 = 8,388,608 slots
// pool2 bf16 [1024 tb][128 ci][64 s]                =  8,388,608 u16 = 4,194,304 slots
#define OFF_POOL1   0u
#define OFF_POOL2   8388608u
#define OFF_FC1OUT  12582912u   // f32 [8,128,256] = 262,144
#define OFF_STATS   12845056u   // f32 768 (contiguous after fc1_out for the zero pass)
#define OFF_FC1S    12845824u   // f32 262,144
#define OFF_A2      13107968u   // bf16 3x[18 kc][128 co][4 q][8 j] = 3*73,728 u16 = 110,592 slots
// total 13,218,560 floats = 52.9 MB
#define ZERO_N      262912u     // fc1_out + stats

__global__ __launch_bounds__(256) void zero_kernel(float* __restrict__ p, unsigned n) {
  unsigned i = blockIdx.x * 256u + threadIdx.x;
  if (i < n) p[i] = 0.0f;
}

// conv2_w [co 128][ci 64][dy 3][dx 3] fp32 -> 3-way bf16 split in MFMA A-frag order:
// k = (dy*3+dx)*64 + ci;  A2[var][ ((kc*128+co)*4 + q)*8 + j ], kc=k>>5, q=(k>>3)&3, j=k&7
__global__ __launch_bounds__(256) void prep_w2(const float* __restrict__ w, unsigned short* __restrict__ A2) {
  int i = blockIdx.x * 256 + threadIdx.x;
  if (i >= 73728) return;
  int co = i / 576, r = i - co * 576;
  int ci = r / 9, t9 = r - ci * 9;
  int k = t9 * 64 + ci;
  int kc = k >> 5, q = (k >> 3) & 3, j = k & 7;
  int off = ((kc * 128 + co) * 4 + q) * 8 + j;
  float wv = w[i];
  unsigned short hi = f2bf(wv);
  float rem = wv - bf2f(hi);
  unsigned short lo = f2bf(rem);
  float rem2 = rem - bf2f(lo);
  unsigned short ll = f2bf(rem2);
  A2[off] = hi;
  A2[73728 + off] = lo;
  A2[147456 + off] = ll;
}

// ---- conv1 pass 1: stats only. Block per (t,b) image. (validated) ----
__global__ __launch_bounds__(256) void conv1_pass1(const float* __restrict__ x,
                                                   const float* __restrict__ w,
                                                   float* __restrict__ s_sum,
                                                   float* __restrict__ s_sq) {
  int tb = blockIdx.x;
  __shared__ float simg[3 * 32 * 36];
  int tid = threadIdx.x;
  const float* xb = x + tb * 3072;
  for (int i = tid; i < 3456; i += 256) {
    int ci = i / 1152, rem = i - ci * 1152;
    int y = rem / 36, px = rem - y * 36;
    int gx = px - 1;
    simg[i] = ((unsigned)gx < 32u) ? xb[(ci * 32 + y) * 32 + gx] : 0.0f;
  }
  __syncthreads();

  int cgrp = tid >> 3, rowthr = tid & 7;
  int c0 = cgrp * 2;
  float w0[27], w1[27];
#pragma unroll
  for (int j = 0; j < 27; ++j) { w0[j] = w[c0 * 27 + j]; w1[j] = w[c0 * 27 + 27 + j]; }

  float s1a = 0.f, s2a = 0.f, s1b = 0.f, s2b = 0.f;
  for (int task = 0; task < 8; ++task) {
    int y = rowthr + (task & 3) * 8;
    int x0 = (task >> 2) * 16;
    float acc0[16] = {0.f,0.f,0.f,0.f,0.f,0.f,0.f,0.f,0.f,0.f,0.f,0.f,0.f,0.f,0.f,0.f};
    float acc1[16] = {0.f,0.f,0.f,0.f,0.f,0.f,0.f,0.f,0.f,0.f,0.f,0.f,0.f,0.f,0.f,0.f};
#pragma unroll
    for (int ci = 0; ci < 3; ++ci) {
#pragma unroll
      for (int dy = 0; dy < 3; ++dy) {
        int yy = y + dy - 1;
        if (yy >= 0 && yy < 32) {
          const float* row = simg + (ci * 32 + yy) * 36 + x0;
          float rr[20];
#pragma unroll
          for (int q = 0; q < 5; ++q) {
            float4 f = *(const float4*)(row + q * 4);
            rr[q*4+0] = f.x; rr[q*4+1] = f.y; rr[q*4+2] = f.z; rr[q*4+3] = f.w;
          }
#pragma unroll
          for (int dx = 0; dx < 3; ++dx) {
            float wa = w0[ci*9 + dy*3 + dx], wb = w1[ci*9 + dy*3 + dx];
#pragma unroll
            for (int xi = 0; xi < 16; ++xi) {
              float v = rr[xi + dx];
              acc0[xi] = fmaf(wa, v, acc0[xi]);
              acc1[xi] = fmaf(wb, v, acc1[xi]);
            }
          }
        }
      }
    }
#pragma unroll
    for (int xi = 0; xi < 16; ++xi) {
      s1a += acc0[xi]; s2a = fmaf(acc0[xi], acc0[xi], s2a);
      s1b += acc1[xi]; s2b = fmaf(acc1[xi], acc1[xi], s2b);
    }
  }
#pragma unroll
  for (int off = 1; off < 8; off <<= 1) {
    s1a += __shfl_xor(s1a, off); s2a += __shfl_xor(s2a, off);
    s1b += __shfl_xor(s1b, off); s2b += __shfl_xor(s2b, off);
  }
  if (rowthr == 0) {
    atomicAdd(&s_sum[c0], s1a);     atomicAdd(&s_sq[c0], s2a);
    atomicAdd(&s_sum[c0 + 1], s1b); atomicAdd(&s_sq[c0 + 1], s2b);
  }
}

__global__ void finalize_bn(const float* __restrict__ sum, const float* __restrict__ sq,
                            const float* __restrict__ g, const float* __restrict__ b,
                            float* __restrict__ scale, float* __restrict__ shift, float inv_n) {
  int c = threadIdx.x;
  float mean = sum[c] * inv_n;
  float var = fmaxf(sq[c] * inv_n - mean * mean, 0.0f);
  float rstd = rsqrtf(var + 1e-5f);
  float sc = g[c] * rstd;
  scale[c] = sc;
  shift[c] = fmaf(-mean, sc, b[c]);
}

// ---- conv1 pass 2: fused conv+BN+LIF+pool. Output layout [tb][cg][py][px][ci_l 8]. ----
// Block = (b, cg); thread = (co_l 0..7, y 0..31).
__global__ __launch_bounds__(256) void conv1_fused(const float* __restrict__ x,
    const float* __restrict__ w, const float* __restrict__ scale, const float* __restrict__ shift,
    unsigned short* __restrict__ pool1) {
  int b = blockIdx.x >> 3, cg = blockIdx.x & 7;
  int tid = threadIdx.x;
  int co_l = tid >> 5;
  int co = cg * 8 + co_l;
  int y = tid & 31;
  __shared__ float simg[3 * 34 * 36];
  __shared__ unsigned short shp[2112];   // [py 16][px 16][co_l 8], row stride 132 u16
  float wreg[27];
#pragma unroll
  for (int j = 0; j < 27; ++j) wreg[j] = w[co * 27 + j];
  float sc = scale[co], sh = shift[co];
  float v[32];
#pragma unroll
  for (int i = 0; i < 32; ++i) v[i] = 0.f;

  for (int t = 0; t < 8; ++t) {
    int tb = t * 128 + b;
    const float* xb = x + tb * 3072;
    __syncthreads();
    for (int i = tid; i < 3672; i += 256) {
      int ci = i / 1224, r = i - ci * 1224;
      int yy = r / 36, xx = r - yy * 36;
      int gy = yy - 1, gx = xx - 1;
      simg[i] = ((unsigned)gy < 32u && (unsigned)gx < 32u) ? xb[(ci * 32 + gy) * 32 + gx] : 0.f;
    }
    __syncthreads();
    float acc[32];
#pragma unroll
    for (int i = 0; i < 32; ++i) acc[i] = 0.f;
#pragma unroll
    for (int ci = 0; ci < 3; ++ci) {
#pragma unroll
      for (int dy = 0; dy < 3; ++dy) {
        const float* row = simg + (ci * 34 + y + dy) * 36;
        float rr[36];
#pragma unroll
        for (int q = 0; q < 9; ++q) {
          float4 f = *(const float4*)(row + q * 4);
          rr[q*4+0]=f.x; rr[q*4+1]=f.y; rr[q*4+2]=f.z; rr[q*4+3]=f.w;
        }
#pragma unroll
        for (int dx = 0; dx < 3; ++dx) {
          float wv = wreg[ci * 9 + dy * 3 + dx];
#pragma unroll
          for (int xx2 = 0; xx2 < 32; ++xx2)
            acc[xx2] = fmaf(wv, rr[xx2 + dx], acc[xx2]);
        }
      }
    }
    // BN + LIF + 2x1 horizontal pool
    float hp[16];
#pragma unroll
    for (int px = 0; px < 16; ++px) {
      float s0, s1, xv;
      xv = fmaf(acc[2*px],   sc, sh); LIF_STEP(v[2*px],   xv, s0);
      xv = fmaf(acc[2*px+1], sc, sh); LIF_STEP(v[2*px+1], xv, s1);
      hp[px] = s0 + s1;
    }
    // vertical pool with lane y^1; even-y lanes write to LDS stage
    unsigned short ob[16];
#pragma unroll
    for (int px = 0; px < 16; ++px) {
      float sum = hp[px] + __shfl_xor(hp[px], 1);
      ob[px] = f2bf(0.25f * sum);
    }
    if ((y & 1) == 0) {
      int py = y >> 1;
#pragma unroll
      for (int px = 0; px < 16; ++px)
        shp[py * 132 + px * 8 + co_l] = ob[px];
    }
    __syncthreads();
    // coalesced copy-out: thread = pixel, 8 ci_l contiguous (16B)
    {
      int py2 = tid >> 4, px2 = tid & 15;
      int o = py2 * 132 + px2 * 8;
      uint2 lo = *(const uint2*)&shp[o];
      uint2 hi = *(const uint2*)&shp[o + 4];
      *(uint4*)(pool1 + (size_t)tb * 16384 + cg * 2048 + tid * 8) = make_uint4(lo.x, lo.y, hi.x, hi.y);
    }
  }
}

// ---- conv2 pass 1 (MFMA): stats only. Block per tb image; 4 waves cover co 128. ----
// LDS image: [row 18][cg 8][x 18][ci_l 8] bf16, zero-padded borders.
__global__ __launch_bounds__(256, 2) void conv2_pass1_mfma(const unsigned short* __restrict__ pool1,
    const unsigned short* __restrict__ A2,
    float* __restrict__ s_sum, float* __restrict__ s_sq) {
  int tb = blockIdx.x;
  __shared__ unsigned short simg[18 * 8 * 18 * 8];   // 41,472 B
  int tid = threadIdx.x;
  const unsigned* src = (const unsigned*)(pool1 + (size_t)tb * 16384);
  unsigned* dstw = (unsigned*)simg;
  for (int i = tid; i < 10368; i += 256) {
    int j = i / 72, r = i - j * 72;       // j = row*8+cg
    int row = j >> 3, cg = j & 7;
    int xx = r >> 2, cp = r & 3;
    int yi = row - 1, gx = xx - 1;
    unsigned val = 0u;
    if ((unsigned)yi < 16u && (unsigned)gx < 16u)
      val = src[cg * 1024 + yi * 64 + gx * 4 + cp];
    dstw[i] = val;
  }
  __syncthreads();

  int wave = tid >> 6, lane = tid & 63;
  int xl = lane & 15, q = lane >> 4;
  int m0 = wave * 32;
  f32x4 acc[2][16];
#pragma unroll
  for (int mt = 0; mt < 2; ++mt)
#pragma unroll
    for (int yy = 0; yy < 16; ++yy) acc[mt][yy] = (f32x4){0.f, 0.f, 0.f, 0.f};

#pragma unroll 1
  for (int kc = 0; kc < 18; ++kc) {
    int tap = kc >> 1;
    int dy = tap / 3, dx = tap - dy * 3;
    int cgq = (kc & 1) * 4 + q;
    short8 a[2][3];
#pragma unroll
    for (int mt = 0; mt < 2; ++mt) {
      int aoff = ((kc * 128 + m0 + mt * 16 + xl) * 4 + q) * 8;
      a[mt][0] = *(const short8*)(A2 + aoff);
      a[mt][1] = *(const short8*)(A2 + 73728 + aoff);
      a[mt][2] = *(const short8*)(A2 + 147456 + aoff);
    }
#pragma unroll
    for (int yy = 0; yy < 16; ++yy) {
      int baddr = (((yy + dy) * 8 + cgq) * 18 + (xl + dx)) * 8;
      short8 bb = *(const short8*)(simg + baddr);
#pragma unroll
      for (int mt = 0; mt < 2; ++mt) {
        acc[mt][yy] = __builtin_amdgcn_mfma_f32_16x16x32_bf16(a[mt][0], bb, acc[mt][yy], 0, 0, 0);
        acc[mt][yy] = __builtin_amdgcn_mfma_f32_16x16x32_bf16(a[mt][1], bb, acc[mt][yy], 0, 0, 0);
        acc[mt][yy] = __builtin_amdgcn_mfma_f32_16x16x32_bf16(a[mt][2], bb, acc[mt][yy], 0, 0, 0);
      }
    }
  }
  // reduce: sum over rows (in-reg), then over x lanes, atomically into per-channel stats
#pragma unroll
  for (int mt = 0; mt < 2; ++mt)
#pragma unroll
    for (int reg = 0; reg < 4; ++reg) {
      float s1 = 0.f, s2 = 0.f;
#pragma unroll
      for (int yy = 0; yy < 16; ++yy) {
        float val = acc[mt][yy][reg];
        s1 += val; s2 = fmaf(val, val, s2);
      }
#pragma unroll
      for (int off = 1; off < 16; off <<= 1) {
        s1 += __shfl_xor(s1, off); s2 += __shfl_xor(s2, off);
      }
      if (xl == 0) {
        int co = m0 + mt * 16 + q * 4 + reg;
        atomicAdd(&s_sum[co], s1);
        atomicAdd(&s_sq[co], s2);
      }
    }
}

// ---- conv2 pass 2 (MFMA): fused conv+BN+LIF+pool. Block = (b, quarter of rows). ----
// t-grouped x2; membrane state v in C-frag registers across all 8 t.
__global__ __launch_bounds__(256, 2) void conv2_fused_mfma(const unsigned short* __restrict__ pool1,
    const unsigned short* __restrict__ A2,
    const float* __restrict__ scale, const float* __restrict__ shift,
    unsigned short* __restrict__ pool2) {
  int b = blockIdx.x >> 2, q4 = blockIdx.x & 3;
  __shared__ unsigned short simg[2 * 6 * 8 * 18 * 8];  // 2 images x 6 rows = 55,296 B
  __shared__ unsigned short shout[128 * 18];           // [ci 128][s_local 16], stride 18
  int tid = threadIdx.x, wave = tid >> 6, lane = tid & 63;
  int xl = lane & 15, q = lane >> 4;
  int m0 = wave * 32;

  float scr[2][4], shr[2][4];
#pragma unroll
  for (int mt = 0; mt < 2; ++mt)
#pragma unroll
    for (int reg = 0; reg < 4; ++reg) {
      int co = m0 + mt * 16 + q * 4 + reg;
      scr[mt][reg] = scale[co]; shr[mt][reg] = shift[co];
    }
  float v[2][4][4];
#pragma unroll
  for (int mt = 0; mt < 2; ++mt)
#pragma unroll
    for (int yl = 0; yl < 4; ++yl)
#pragma unroll
      for (int reg = 0; reg < 4; ++reg) v[mt][yl][reg] = 0.f;

#pragma unroll 1
  for (int tg = 0; tg < 4; ++tg) {
    __syncthreads();
    // stage 2 images, rows q4*4-1 .. q4*4+4, layout [t_l][row 6][cg 8][x 18][ci_l 8]
    for (int i = tid; i < 6912; i += 256) {
      int t_l = i / 3456, r1 = i - t_l * 3456;
      int j = r1 / 72, r = r1 - j * 72;
      int row_l = j >> 3, cg = j & 7;
      int xx = r >> 2, cp = r & 3;
      int yi = q4 * 4 - 1 + row_l, gx = xx - 1;
      unsigned val = 0u;
      if ((unsigned)yi < 16u && (unsigned)gx < 16u)
        val = ((const unsigned*)pool1)[(size_t)((tg * 2 + t_l) * 128 + b) * 8192 + cg * 1024 + yi * 64 + gx * 4 + cp];
      ((unsigned*)simg)[i] = val;
    }
    __syncthreads();

    f32x4 acc[2][2][4];   // [t_l][mt][yl]
#pragma unroll
    for (int t_l = 0; t_l < 2; ++t_l)
#pragma unroll
      for (int mt = 0; mt < 2; ++mt)
#pragma unroll
        for (int yl = 0; yl < 4; ++yl) acc[t_l][mt][yl] = (f32x4){0.f, 0.f, 0.f, 0.f};

#pragma unroll 1
    for (int kc = 0; kc < 18; ++kc) {
      int tap = kc >> 1;
      int dy = tap / 3, dx = tap - dy * 3;
      int cgq = (kc & 1) * 4 + q;
      short8 a[2][3];
#pragma unroll
      for (int mt = 0; mt < 2; ++mt) {
        int aoff = ((kc * 128 + m0 + mt * 16 + xl) * 4 + q) * 8;
        a[mt][0] = *(const short8*)(A2 + aoff);
        a[mt][1] = *(const short8*)(A2 + 73728 + aoff);
        a[mt][2] = *(const short8*)(A2 + 147456 + aoff);
      }
#pragma unroll
      for (int t_l = 0; t_l < 2; ++t_l) {
        int base_t = t_l * 6912;
#pragma unroll
        for (int yl = 0; yl < 4; ++yl) {
          int baddr = base_t + (((yl + dy) * 8 + cgq) * 18 + (xl + dx)) * 8;
          short8 bb = *(const short8*)(simg + baddr);
#pragma unroll
          for (int mt = 0; mt < 2; ++mt) {
            acc[t_l][mt][yl] = __builtin_amdgcn_mfma_f32_16x16x32_bf16(a[mt][0], bb, acc[t_l][mt][yl], 0, 0, 0);
            acc[t_l][mt][yl] = __builtin_amdgcn_mfma_f32_16x16x32_bf16(a[mt][1], bb, acc[t_l][mt][yl], 0, 0, 0);
            acc[t_l][mt][yl] = __builtin_amdgcn_mfma_f32_16x16x32_bf16(a[mt][2], bb, acc[t_l][mt][yl], 0, 0, 0);
          }
        }
      }
    }

    // epilogue per t (order matters for LIF)
#pragma unroll 1
    for (int t_l = 0; t_l < 2; ++t_l) {
      __syncthreads();   // previous shout copy-out complete
#pragma unroll
      for (int mt = 0; mt < 2; ++mt)
#pragma unroll
        for (int reg = 0; reg < 4; ++reg) {
          float sarr[4];
#pragma unroll
          for (int yl = 0; yl < 4; ++yl) {
            float xv = fmaf(acc[t_l][mt][yl][reg], scr[mt][reg], shr[mt][reg]);
            float spk;
            LIF_STEP(v[mt][yl][reg], xv, spk);
            sarr[yl] = spk;
          }
#pragma unroll
          for (int rp = 0; rp < 2; ++rp) {
            float hp0 = sarr[2*rp]     + __shfl_xor(sarr[2*rp], 1);
            float hp1 = sarr[2*rp + 1] + __shfl_xor(sarr[2*rp + 1], 1);
            float vp = hp0 + hp1;
            if ((xl & 1) == 0) {
              int co = m0 + mt * 16 + q * 4 + reg;
              shout[co * 18 + rp * 8 + (xl >> 1)] = f2bf(0.25f * vp);
            }
          }
        }
      __syncthreads();
      // coalesced copy-out: pool2 layout [tb][ci 128][s 64] (fc1-compatible)
      {
        int ci = tid >> 1, half = tid & 1;
        const unsigned* sp = (const unsigned*)&shout[ci * 18 + half * 8];
        unsigned u0 = sp[0], u1 = sp[1], u2 = sp[2], u3 = sp[3];
        int t = tg * 2 + t_l;
        unsigned short* dst = pool2 + (size_t)(t * 128 + b) * 8192 + ci * 64 + q4 * 16 + half * 8;
        *(uint4*)dst = make_uint4(u0, u1, u2, u3);
      }
    }
  }
}

// ---- fc1: C[1024,256] = A_bf16[1024,8192] * B[256,8192]^T, split-K=32 atomic. (validated) ----
__global__ __launch_bounds__(256) void fc1_gemm(const unsigned short* __restrict__ A,
                                                const float* __restrict__ B,
                                                float* __restrict__ C) {
  __shared__ float As[16][128];
  __shared__ float Bs[16][128];
  int tid = threadIdx.x;
  int tx = tid & 15, ty = tid >> 4;
  int M0 = blockIdx.x * 128;
  int N0 = blockIdx.y * 128;
  int K0 = blockIdx.z * 256;
  float acc[8][8] = {};
  for (int kc = 0; kc < 256; kc += 16) {
#pragma unroll
    for (int i = 0; i < 2; ++i) {
      int task = tid + 256 * i;
      int m = task >> 2, qq = task & 3;
      uint2 a2 = *(const uint2*)(A + (size_t)(M0 + m) * 8192 + K0 + kc + qq * 4);
      As[qq*4+0][m] = bf2f((unsigned short)(a2.x & 0xffffu));
      As[qq*4+1][m] = bf2f((unsigned short)(a2.x >> 16));
      As[qq*4+2][m] = bf2f((unsigned short)(a2.y & 0xffffu));
      As[qq*4+3][m] = bf2f((unsigned short)(a2.y >> 16));
      float4 b4 = *(const float4*)(B + (size_t)(N0 + m) * 8192 + K0 + kc + qq * 4);
      Bs[qq*4+0][m] = b4.x; Bs[qq*4+1][m] = b4.y; Bs[qq*4+2][m] = b4.z; Bs[qq*4+3][m] = b4.w;
    }
    __syncthreads();
#pragma unroll
    for (int kk = 0; kk < 16; ++kk) {
      float4 a0 = *(const float4*)&As[kk][ty * 8];
      float4 a1 = *(const float4*)&As[kk][ty * 8 + 4];
      float4 b0 = *(const float4*)&Bs[kk][tx * 8];
      float4 b1 = *(const float4*)&Bs[kk][tx * 8 + 4];
      float av[8] = {a0.x,a0.y,a0.z,a0.w,a1.x,a1.y,a1.z,a1.w};
      float bv[8] = {b0.x,b0.y,b0.z,b0.w,b1.x,b1.y,b1.z,b1.w};
#pragma unroll
      for (int i = 0; i < 8; ++i)
#pragma unroll
        for (int j = 0; j < 8; ++j)
          acc[i][j] = fmaf(av[i], bv[j], acc[i][j]);
    }
    __syncthreads();
  }
#pragma unroll
  for (int i = 0; i < 8; ++i)
#pragma unroll
    for (int j = 0; j < 8; ++j)
      atomicAdd(&C[(M0 + ty * 8 + i) * 256 + N0 + tx * 8 + j], acc[i][j]);
}

__global__ __launch_bounds__(256) void lif_fc(const float* __restrict__ fin, float* __restrict__ fs) {
  int idx = blockIdx.x * 256 + threadIdx.x;
  float v = 0.f;
#pragma unroll
  for (int t = 0; t < 8; ++t) {
    float xv = fin[t * 32768 + idx], s;
    LIF_STEP(v, xv, s);
    fs[t * 32768 + idx] = s;
  }
}

__global__ __launch_bounds__(256) void fc2_kernel(const float* __restrict__ fs, const float* __restrict__ w,
                                                  const float* __restrict__ bias, float* __restrict__ outp) {
  int tb = blockIdx.x;
  __shared__ float sv[256];
  int tid = threadIdx.x;
  sv[tid] = fs[tb * 256 + tid];
  __syncthreads();
  if (tid < 10) {
    float a = bias[tid];
    const float* wr = w + tid * 256;
#pragma unroll 8
    for (int o = 0; o < 256; ++o) a = fmaf(sv[o], wr[o], a);
    outp[tb * 10 + tid] = a;
  }
}

extern "C" void kernel_launch(void* const* d_in, const int* in_sizes, int n_in,
                              void* d_out, int out_size, void* d_ws, size_t ws_size,
                              hipStream_t stream) {
  (void)in_sizes; (void)n_in; (void)out_size; (void)ws_size;
  const float* x_seq   = (const float*)d_in[0];
  const float* conv1_w = (const float*)d_in[1];
  const float* bn1_g   = (const float*)d_in[2];
  const float* bn1_b   = (const float*)d_in[3];
  const float* conv2_w = (const float*)d_in[4];
  const float* bn2_g   = (const float*)d_in[5];
  const float* bn2_b   = (const float*)d_in[6];
  const float* fc1_w   = (const float*)d_in[7];
  const float* fc2_w   = (const float*)d_in[8];
  const float* fc2_b   = (const float*)d_in[9];
  float* out = (float*)d_out;
  float* ws  = (float*)d_ws;

  unsigned short* pool1 = (unsigned short*)(ws + OFF_POOL1);
  unsigned short* pool2 = (unsigned short*)(ws + OFF_POOL2);
  float* fc1_out = ws + OFF_FC1OUT;
  float* fc1_s   = ws + OFF_FC1S;
  unsigned short* A2 = (unsigned short*)(ws + OFF_A2);
  float* st      = ws + OFF_STATS;
  float* s1_sum = st;        float* s1_sq  = st + 64;
  float* bn1_sc = st + 128;  float* bn1_sh = st + 192;
  float* s2_sum = st + 256;  float* s2_sq  = st + 384;
  float* bn2_sc = st + 512;  float* bn2_sh = st + 640;

  // 1. zero fc1_out + stats
  zero_kernel<<<1027, 256, 0, stream>>>(fc1_out, ZERO_N);
  // 2. conv2 weight 3-way bf16 split into MFMA A-frag layout
  prep_w2<<<288, 256, 0, stream>>>(conv2_w, A2);
  // 3. conv1 stats
  conv1_pass1<<<1024, 256, 0, stream>>>(x_seq, conv1_w, s1_sum, s1_sq);
  // 4. BN1 finalize
  finalize_bn<<<1, 64, 0, stream>>>(s1_sum, s1_sq, bn1_g, bn1_b, bn1_sc, bn1_sh, 1.0f / 1048576.0f);
  // 5. fused conv1+BN+LIF+pool -> pool1 (bf16, conv2-friendly layout)
  conv1_fused<<<1024, 256, 0, stream>>>(x_seq, conv1_w, bn1_sc, bn1_sh, pool1);
  // 6. conv2 stats via MFMA
  conv2_pass1_mfma<<<1024, 256, 0, stream>>>(pool1, A2, s2_sum, s2_sq);
  // 7. BN2 finalize
  finalize_bn<<<1, 128, 0, stream>>>(s2_sum, s2_sq, bn2_g, bn2_b, bn2_sc, bn2_sh, 1.0f / 262144.0f);
  // 8. fused conv2+BN+LIF+pool via MFMA -> pool2 [tb][ci][s]
  conv2_fused_mfma<<<512, 256, 0, stream>>>(pool1, A2, bn2_sc, bn2_sh, pool2);
  // 9. fc1 GEMM (split-K atomics into zeroed fc1_out)
  fc1_gemm<<<dim3(8, 2, 32), 256, 0, stream>>>(pool2, fc1_w, fc1_out);
  // 10. LIF over fc1
  lif_fc<<<128, 256, 0, stream>>>(fc1_out, fc1_s);
  // 11. fc2 + bias -> logits [8,128,10]
  fc2_kernel<<<1024, 256, 0, stream>>>(fc1_s, fc2_w, fc2_b, out);
}

// Round 4
// 662.790 us; speedup vs baseline: 5.6856x; 1.5010x over previous
//
#include <hip/hip_runtime.h>

// SNN forward. conv2 AND fc1 on MFMA bf16 with 3-way weight splits (hi+lo+lolo;
// residual ~2^-24 rel). Spike inputs exact in bf16; accumulate fp32.
//   conv1 stats -> bn1 -> fused conv1+BN+LIF+pool (bf16 spikes, conv2-friendly layout)
//   conv2 stats (MFMA) -> bn2 -> fused conv2+BN+LIF+pool (MFMA, membrane in C-frag regs)
//   fc1 MFMA (split-K=16, private partials, NO atomics) -> reduce+LIF -> fc2

#define LIF_STEP(vv, xx, ss) do { \
    vv = fmaf((xx) - vv, 0.5f, vv); \
    ss = (vv >= 1.0f) ? 1.0f : 0.0f; \
    vv = (vv >= 1.0f) ? 0.0f : vv; \
  } while (0)

typedef __attribute__((ext_vector_type(8))) short short8;
typedef __attribute__((ext_vector_type(4))) float f32x4;

__device__ __forceinline__ float bf2f(unsigned short u) {
  return __uint_as_float(((unsigned)u) << 16);
}
__device__ __forceinline__ unsigned short f2bf(float f) {
  return (unsigned short)(__float_as_uint(f) >> 16);  // truncation; exact for k/4 spike values
}

// ---- workspace layout (float-slot offsets) ----
// pool1 bf16 [1024 tb][8 cg][16 py][16 px][8 ci_l] = 16,777,216 u16 = 8,388,608 slots
//   (region reused AFTER conv2 as fc1 partials: f32 [16 kb][256 o][1024 tb] = 4,194,304 slots)
// pool2 bf16 [1024 tb][128 ci][64 s]               =  8,388,608 u16 = 4,194,304 slots
#define OFF_POOL1   0u
#define OFF_POOL2   8388608u
#define OFF_STATS   12582912u   // f32 768
#define OFF_FC1S    12583680u   // f32 262,144
#define OFF_A2      12845824u   // bf16 3x[18 kc][128 co][4 q][8 j] = 110,592 slots
#define OFF_B1      12956416u   // bf16 3x[256 kc][256 o][4 q][8 j] = 3x2,097,152 u16 = 3,145,728 slots
// total 16,102,144 floats = 64.4 MB

__global__ __launch_bounds__(256) void zero_kernel(float* __restrict__ p, unsigned n) {
  unsigned i = blockIdx.x * 256u + threadIdx.x;
  if (i < n) p[i] = 0.0f;
}

// conv2_w [co 128][ci 64][dy 3][dx 3] fp32 -> 3-way bf16 split in MFMA A-frag order
__global__ __launch_bounds__(256) void prep_w2(const float* __restrict__ w, unsigned short* __restrict__ A2) {
  int i = blockIdx.x * 256 + threadIdx.x;
  if (i >= 73728) return;
  int co = i / 576, r = i - co * 576;
  int ci = r / 9, t9 = r - ci * 9;
  int k = t9 * 64 + ci;
  int kc = k >> 5, q = (k >> 3) & 3, j = k & 7;
  int off = ((kc * 128 + co) * 4 + q) * 8 + j;
  float wv = w[i];
  unsigned short hi = f2bf(wv);
  float rem = wv - bf2f(hi);
  unsigned short lo = f2bf(rem);
  float rem2 = rem - bf2f(lo);
  A2[off] = hi;
  A2[73728 + off] = lo;
  A2[147456 + off] = f2bf(rem2);
}

// fc1_w [o 256][k 8192] fp32 -> 3-way bf16 split in MFMA A-frag order:
// B1[var][ ((kc*256 + o)*4 + q)*8 + j ], kc=k>>5, q=(k>>3)&3, j=k&7
__global__ __launch_bounds__(256) void prep_b1(const float* __restrict__ w, unsigned short* __restrict__ B1) {
  int i = blockIdx.x * 256 + threadIdx.x;   // 2,097,152 total
  int o = i >> 13, k = i & 8191;
  int kc = k >> 5, q = (k >> 3) & 3, j = k & 7;
  int off = ((kc * 256 + o) * 4 + q) * 8 + j;
  float wv = w[i];
  unsigned short hi = f2bf(wv);
  float rem = wv - bf2f(hi);
  unsigned short lo = f2bf(rem);
  float rem2 = rem - bf2f(lo);
  B1[off] = hi;
  B1[2097152 + off] = lo;
  B1[4194304 + off] = f2bf(rem2);
}

// ---- conv1 pass 1: stats only. Block per (t,b) image. (validated) ----
__global__ __launch_bounds__(256) void conv1_pass1(const float* __restrict__ x,
                                                   const float* __restrict__ w,
                                                   float* __restrict__ s_sum,
                                                   float* __restrict__ s_sq) {
  int tb = blockIdx.x;
  __shared__ float simg[3 * 32 * 36];
  int tid = threadIdx.x;
  const float* xb = x + tb * 3072;
  for (int i = tid; i < 3456; i += 256) {
    int ci = i / 1152, rem = i - ci * 1152;
    int y = rem / 36, px = rem - y * 36;
    int gx = px - 1;
    simg[i] = ((unsigned)gx < 32u) ? xb[(ci * 32 + y) * 32 + gx] : 0.0f;
  }
  __syncthreads();

  int cgrp = tid >> 3, rowthr = tid & 7;
  int c0 = cgrp * 2;
  float w0[27], w1[27];
#pragma unroll
  for (int j = 0; j < 27; ++j) { w0[j] = w[c0 * 27 + j]; w1[j] = w[c0 * 27 + 27 + j]; }

  float s1a = 0.f, s2a = 0.f, s1b = 0.f, s2b = 0.f;
  for (int task = 0; task < 8; ++task) {
    int y = rowthr + (task & 3) * 8;
    int x0 = (task >> 2) * 16;
    float acc0[16] = {0.f,0.f,0.f,0.f,0.f,0.f,0.f,0.f,0.f,0.f,0.f,0.f,0.f,0.f,0.f,0.f};
    float acc1[16] = {0.f,0.f,0.f,0.f,0.f,0.f,0.f,0.f,0.f,0.f,0.f,0.f,0.f,0.f,0.f,0.f};
#pragma unroll
    for (int ci = 0; ci < 3; ++ci) {
#pragma unroll
      for (int dy = 0; dy < 3; ++dy) {
        int yy = y + dy - 1;
        if (yy >= 0 && yy < 32) {
          const float* row = simg + (ci * 32 + yy) * 36 + x0;
          float rr[20];
#pragma unroll
          for (int q = 0; q < 5; ++q) {
            float4 f = *(const float4*)(row + q * 4);
            rr[q*4+0] = f.x; rr[q*4+1] = f.y; rr[q*4+2] = f.z; rr[q*4+3] = f.w;
          }
#pragma unroll
          for (int dx = 0; dx < 3; ++dx) {
            float wa = w0[ci*9 + dy*3 + dx], wb = w1[ci*9 + dy*3 + dx];
#pragma unroll
            for (int xi = 0; xi < 16; ++xi) {
              float v = rr[xi + dx];
              acc0[xi] = fmaf(wa, v, acc0[xi]);
              acc1[xi] = fmaf(wb, v, acc1[xi]);
            }
          }
        }
      }
    }
#pragma unroll
    for (int xi = 0; xi < 16; ++xi) {
      s1a += acc0[xi]; s2a = fmaf(acc0[xi], acc0[xi], s2a);
      s1b += acc1[xi]; s2b = fmaf(acc1[xi], acc1[xi], s2b);
    }
  }
#pragma unroll
  for (int off = 1; off < 8; off <<= 1) {
    s1a += __shfl_xor(s1a, off); s2a += __shfl_xor(s2a, off);
    s1b += __shfl_xor(s1b, off); s2b += __shfl_xor(s2b, off);
  }
  if (rowthr == 0) {
    atomicAdd(&s_sum[c0], s1a);     atomicAdd(&s_sq[c0], s2a);
    atomicAdd(&s_sum[c0 + 1], s1b); atomicAdd(&s_sq[c0 + 1], s2b);
  }
}

__global__ void finalize_bn(const float* __restrict__ sum, const float* __restrict__ sq,
                            const float* __restrict__ g, const float* __restrict__ b,
                            float* __restrict__ scale, float* __restrict__ shift, float inv_n) {
  int c = threadIdx.x;
  float mean = sum[c] * inv_n;
  float var = fmaxf(sq[c] * inv_n - mean * mean, 0.0f);
  float rstd = rsqrtf(var + 1e-5f);
  float sc = g[c] * rstd;
  scale[c] = sc;
  shift[c] = fmaf(-mean, sc, b[c]);
}

// ---- conv1 pass 2: fused conv+BN+LIF+pool. Output layout [tb][cg][py][px][ci_l 8]. ----
__global__ __launch_bounds__(256) void conv1_fused(const float* __restrict__ x,
    const float* __restrict__ w, const float* __restrict__ scale, const float* __restrict__ shift,
    unsigned short* __restrict__ pool1) {
  int b = blockIdx.x >> 3, cg = blockIdx.x & 7;
  int tid = threadIdx.x;
  int co_l = tid >> 5;
  int co = cg * 8 + co_l;
  int y = tid & 31;
  __shared__ float simg[3 * 34 * 36];
  __shared__ unsigned short shp[2112];   // [py 16][px 16][co_l 8], row stride 132 u16
  float wreg[27];
#pragma unroll
  for (int j = 0; j < 27; ++j) wreg[j] = w[co * 27 + j];
  float sc = scale[co], sh = shift[co];
  float v[32];
#pragma unroll
  for (int i = 0; i < 32; ++i) v[i] = 0.f;

  for (int t = 0; t < 8; ++t) {
    int tb = t * 128 + b;
    const float* xb = x + tb * 3072;
    __syncthreads();
    for (int i = tid; i < 3672; i += 256) {
      int ci = i / 1224, r = i - ci * 1224;
      int yy = r / 36, xx = r - yy * 36;
      int gy = yy - 1, gx = xx - 1;
      simg[i] = ((unsigned)gy < 32u && (unsigned)gx < 32u) ? xb[(ci * 32 + gy) * 32 + gx] : 0.f;
    }
    __syncthreads();
    float acc[32];
#pragma unroll
    for (int i = 0; i < 32; ++i) acc[i] = 0.f;
#pragma unroll
    for (int ci = 0; ci < 3; ++ci) {
#pragma unroll
      for (int dy = 0; dy < 3; ++dy) {
        const float* row = simg + (ci * 34 + y + dy) * 36;
        float rr[36];
#pragma unroll
        for (int q = 0; q < 9; ++q) {
          float4 f = *(const float4*)(row + q * 4);
          rr[q*4+0]=f.x; rr[q*4+1]=f.y; rr[q*4+2]=f.z; rr[q*4+3]=f.w;
        }
#pragma unroll
        for (int dx = 0; dx < 3; ++dx) {
          float wv = wreg[ci * 9 + dy * 3 + dx];
#pragma unroll
          for (int xx2 = 0; xx2 < 32; ++xx2)
            acc[xx2] = fmaf(wv, rr[xx2 + dx], acc[xx2]);
        }
      }
    }
    float hp[16];
#pragma unroll
    for (int px = 0; px < 16; ++px) {
      float s0, s1, xv;
      xv = fmaf(acc[2*px],   sc, sh); LIF_STEP(v[2*px],   xv, s0);
      xv = fmaf(acc[2*px+1], sc, sh); LIF_STEP(v[2*px+1], xv, s1);
      hp[px] = s0 + s1;
    }
    unsigned short ob[16];
#pragma unroll
    for (int px = 0; px < 16; ++px) {
      float sum = hp[px] + __shfl_xor(hp[px], 1);
      ob[px] = f2bf(0.25f * sum);
    }
    if ((y & 1) == 0) {
      int py = y >> 1;
#pragma unroll
      for (int px = 0; px < 16; ++px)
        shp[py * 132 + px * 8 + co_l] = ob[px];
    }
    __syncthreads();
    {
      int o = (tid >> 4) * 132 + (tid & 15) * 8;
      uint2 lo = *(const uint2*)&shp[o];
      uint2 hi = *(const uint2*)&shp[o + 4];
      *(uint4*)(pool1 + (size_t)tb * 16384 + cg * 2048 + tid * 8) = make_uint4(lo.x, lo.y, hi.x, hi.y);
    }
  }
}

// ---- conv2 pass 1 (MFMA): stats only. Block per tb image; 4 waves cover co 128. ----
__global__ __launch_bounds__(256, 2) void conv2_pass1_mfma(const unsigned short* __restrict__ pool1,
    const unsigned short* __restrict__ A2,
    float* __restrict__ s_sum, float* __restrict__ s_sq) {
  int tb = blockIdx.x;
  __shared__ unsigned short simg[18 * 8 * 18 * 8];   // 41,472 B
  int tid = threadIdx.x;
  const unsigned* src = (const unsigned*)(pool1 + (size_t)tb * 16384);
  unsigned* dstw = (unsigned*)simg;
  for (int i = tid; i < 10368; i += 256) {
    int j = i / 72, r = i - j * 72;
    int row = j >> 3, cg = j & 7;
    int xx = r >> 2, cp = r & 3;
    int yi = row - 1, gx = xx - 1;
    unsigned val = 0u;
    if ((unsigned)yi < 16u && (unsigned)gx < 16u)
      val = src[cg * 1024 + yi * 64 + gx * 4 + cp];
    dstw[i] = val;
  }
  __syncthreads();

  int wave = tid >> 6, lane = tid & 63;
  int xl = lane & 15, q = lane >> 4;
  int m0 = wave * 32;
  f32x4 acc[2][16];
#pragma unroll
  for (int mt = 0; mt < 2; ++mt)
#pragma unroll
    for (int yy = 0; yy < 16; ++yy) acc[mt][yy] = (f32x4){0.f, 0.f, 0.f, 0.f};

#pragma unroll 1
  for (int kc = 0; kc < 18; ++kc) {
    int tap = kc >> 1;
    int dy = tap / 3, dx = tap - dy * 3;
    int cgq = (kc & 1) * 4 + q;
    short8 a[2][3];
#pragma unroll
    for (int mt = 0; mt < 2; ++mt) {
      int aoff = ((kc * 128 + m0 + mt * 16 + xl) * 4 + q) * 8;
      a[mt][0] = *(const short8*)(A2 + aoff);
      a[mt][1] = *(const short8*)(A2 + 73728 + aoff);
      a[mt][2] = *(const short8*)(A2 + 147456 + aoff);
    }
#pragma unroll
    for (int yy = 0; yy < 16; ++yy) {
      int baddr = (((yy + dy) * 8 + cgq) * 18 + (xl + dx)) * 8;
      short8 bb = *(const short8*)(simg + baddr);
#pragma unroll
      for (int mt = 0; mt < 2; ++mt) {
        acc[mt][yy] = __builtin_amdgcn_mfma_f32_16x16x32_bf16(a[mt][0], bb, acc[mt][yy], 0, 0, 0);
        acc[mt][yy] = __builtin_amdgcn_mfma_f32_16x16x32_bf16(a[mt][1], bb, acc[mt][yy], 0, 0, 0);
        acc[mt][yy] = __builtin_amdgcn_mfma_f32_16x16x32_bf16(a[mt][2], bb, acc[mt][yy], 0, 0, 0);
      }
    }
  }
#pragma unroll
  for (int mt = 0; mt < 2; ++mt)
#pragma unroll
    for (int reg = 0; reg < 4; ++reg) {
      float s1 = 0.f, s2 = 0.f;
#pragma unroll
      for (int yy = 0; yy < 16; ++yy) {
        float val = acc[mt][yy][reg];
        s1 += val; s2 = fmaf(val, val, s2);
      }
#pragma unroll
      for (int off = 1; off < 16; off <<= 1) {
        s1 += __shfl_xor(s1, off); s2 += __shfl_xor(s2, off);
      }
      if (xl == 0) {
        int co = m0 + mt * 16 + q * 4 + reg;
        atomicAdd(&s_sum[co], s1);
        atomicAdd(&s_sq[co], s2);
      }
    }
}

// ---- conv2 pass 2 (MFMA): fused conv+BN+LIF+pool. Block = (b, quarter of rows). ----
__global__ __launch_bounds__(256, 2) void conv2_fused_mfma(const unsigned short* __restrict__ pool1,
    const unsigned short* __restrict__ A2,
    const float* __restrict__ scale, const float* __restrict__ shift,
    unsigned short* __restrict__ pool2) {
  int b = blockIdx.x >> 2, q4 = blockIdx.x & 3;
  __shared__ unsigned short simg[2 * 6 * 8 * 18 * 8];
  __shared__ unsigned short shout[128 * 18];
  int tid = threadIdx.x, wave = tid >> 6, lane = tid & 63;
  int xl = lane & 15, q = lane >> 4;
  int m0 = wave * 32;

  float scr[2][4], shr[2][4];
#pragma unroll
  for (int mt = 0; mt < 2; ++mt)
#pragma unroll
    for (int reg = 0; reg < 4; ++reg) {
      int co = m0 + mt * 16 + q * 4 + reg;
      scr[mt][reg] = scale[co]; shr[mt][reg] = shift[co];
    }
  float v[2][4][4];
#pragma unroll
  for (int mt = 0; mt < 2; ++mt)
#pragma unroll
    for (int yl = 0; yl < 4; ++yl)
#pragma unroll
      for (int reg = 0; reg < 4; ++reg) v[mt][yl][reg] = 0.f;

#pragma unroll 1
  for (int tg = 0; tg < 4; ++tg) {
    __syncthreads();
    for (int i = tid; i < 6912; i += 256) {
      int t_l = i / 3456, r1 = i - t_l * 3456;
      int j = r1 / 72, r = r1 - j * 72;
      int row_l = j >> 3, cg = j & 7;
      int xx = r >> 2, cp = r & 3;
      int yi = q4 * 4 - 1 + row_l, gx = xx - 1;
      unsigned val = 0u;
      if ((unsigned)yi < 16u && (unsigned)gx < 16u)
        val = ((const unsigned*)pool1)[(size_t)((tg * 2 + t_l) * 128 + b) * 8192 + cg * 1024 + yi * 64 + gx * 4 + cp];
      ((unsigned*)simg)[i] = val;
    }
    __syncthreads();

    f32x4 acc[2][2][4];
#pragma unroll
    for (int t_l = 0; t_l < 2; ++t_l)
#pragma unroll
      for (int mt = 0; mt < 2; ++mt)
#pragma unroll
        for (int yl = 0; yl < 4; ++yl) acc[t_l][mt][yl] = (f32x4){0.f, 0.f, 0.f, 0.f};

#pragma unroll 1
    for (int kc = 0; kc < 18; ++kc) {
      int tap = kc >> 1;
      int dy = tap / 3, dx = tap - dy * 3;
      int cgq = (kc & 1) * 4 + q;
      short8 a[2][3];
#pragma unroll
      for (int mt = 0; mt < 2; ++mt) {
        int aoff = ((kc * 128 + m0 + mt * 16 + xl) * 4 + q) * 8;
        a[mt][0] = *(const short8*)(A2 + aoff);
        a[mt][1] = *(const short8*)(A2 + 73728 + aoff);
        a[mt][2] = *(const short8*)(A2 + 147456 + aoff);
      }
#pragma unroll
      for (int t_l = 0; t_l < 2; ++t_l) {
        int base_t = t_l * 6912;
#pragma unroll
        for (int yl = 0; yl < 4; ++yl) {
          int baddr = base_t + (((yl + dy) * 8 + cgq) * 18 + (xl + dx)) * 8;
          short8 bb = *(const short8*)(simg + baddr);
#pragma unroll
          for (int mt = 0; mt < 2; ++mt) {
            acc[t_l][mt][yl] = __builtin_amdgcn_mfma_f32_16x16x32_bf16(a[mt][0], bb, acc[t_l][mt][yl], 0, 0, 0);
            acc[t_l][mt][yl] = __builtin_amdgcn_mfma_f32_16x16x32_bf16(a[mt][1], bb, acc[t_l][mt][yl], 0, 0, 0);
            acc[t_l][mt][yl] = __builtin_amdgcn_mfma_f32_16x16x32_bf16(a[mt][2], bb, acc[t_l][mt][yl], 0, 0, 0);
          }
        }
      }
    }

#pragma unroll 1
    for (int t_l = 0; t_l < 2; ++t_l) {
      __syncthreads();
#pragma unroll
      for (int mt = 0; mt < 2; ++mt)
#pragma unroll
        for (int reg = 0; reg < 4; ++reg) {
          float sarr[4];
#pragma unroll
          for (int yl = 0; yl < 4; ++yl) {
            float xv = fmaf(acc[t_l][mt][yl][reg], scr[mt][reg], shr[mt][reg]);
            float spk;
            LIF_STEP(v[mt][yl][reg], xv, spk);
            sarr[yl] = spk;
          }
#pragma unroll
          for (int rp = 0; rp < 2; ++rp) {
            float hp0 = sarr[2*rp]     + __shfl_xor(sarr[2*rp], 1);
            float hp1 = sarr[2*rp + 1] + __shfl_xor(sarr[2*rp + 1], 1);
            float vp = hp0 + hp1;
            if ((xl & 1) == 0) {
              int co = m0 + mt * 16 + q * 4 + reg;
              shout[co * 18 + rp * 8 + (xl >> 1)] = f2bf(0.25f * vp);
            }
          }
        }
      __syncthreads();
      {
        int ci = tid >> 1, half = tid & 1;
        const unsigned* sp = (const unsigned*)&shout[ci * 18 + half * 8];
        unsigned u0 = sp[0], u1 = sp[1], u2 = sp[2], u3 = sp[3];
        int t = tg * 2 + t_l;
        unsigned short* dst = pool2 + (size_t)(t * 128 + b) * 8192 + ci * 64 + q4 * 16 + half * 8;
        *(uint4*)dst = make_uint4(u0, u1, u2, u3);
      }
    }
  }
}

// ---- fc1 (MFMA): partial[kb][o 256][tb 1024] += W3split x spikes, split-K=16, no atomics. ----
// Block = (t_o, tbt, kb): o-tile 128 (4 waves x 32), tb-tile 64, K-chunk 512.
__global__ __launch_bounds__(256, 2) void fc1_mfma(const unsigned short* __restrict__ pool2,
    const unsigned short* __restrict__ B1, float* __restrict__ partial) {
  int bx = blockIdx.x;            // 512 = kb(16) x tbt(16) x t_o(2)
  int t_o = bx & 1, tbt = (bx >> 1) & 15, kb = bx >> 5;
  int tid = threadIdx.x, wave = tid >> 6, lane = tid & 63;
  int xl = lane & 15, q = lane >> 4;
  int m0 = t_o * 128 + wave * 32;
  int n0 = tbt * 64;
  __shared__ unsigned short sB[64 * 40];   // [tb_l 64][k 32], row stride 40 u16 (2-way banks)
  f32x4 acc[2][4];
#pragma unroll
  for (int mt = 0; mt < 2; ++mt)
#pragma unroll
    for (int nt = 0; nt < 4; ++nt) acc[mt][nt] = (f32x4){0.f, 0.f, 0.f, 0.f};

#pragma unroll 1
  for (int kc0 = 0; kc0 < 16; ++kc0) {
    int kc = kb * 16 + kc0;
    __syncthreads();
    {
      int tb_l = tid >> 2, kq = tid & 3;
      uint4 vv = *(const uint4*)(pool2 + (size_t)(n0 + tb_l) * 8192 + kc * 32 + kq * 8);
      *(uint4*)(sB + tb_l * 40 + kq * 8) = vv;
    }
    __syncthreads();
    short8 a[2][3];
#pragma unroll
    for (int mt = 0; mt < 2; ++mt) {
      int aoff = ((kc * 256 + m0 + mt * 16 + xl) * 4 + q) * 8;
      a[mt][0] = *(const short8*)(B1 + aoff);
      a[mt][1] = *(const short8*)(B1 + 2097152 + aoff);
      a[mt][2] = *(const short8*)(B1 + 4194304 + aoff);
    }
#pragma unroll
    for (int nt = 0; nt < 4; ++nt) {
      short8 bb = *(const short8*)(sB + (nt * 16 + xl) * 40 + q * 8);
#pragma unroll
      for (int mt = 0; mt < 2; ++mt) {
        acc[mt][nt] = __builtin_amdgcn_mfma_f32_16x16x32_bf16(a[mt][0], bb, acc[mt][nt], 0, 0, 0);
        acc[mt][nt] = __builtin_amdgcn_mfma_f32_16x16x32_bf16(a[mt][1], bb, acc[mt][nt], 0, 0, 0);
        acc[mt][nt] = __builtin_amdgcn_mfma_f32_16x16x32_bf16(a[mt][2], bb, acc[mt][nt], 0, 0, 0);
      }
    }
  }
  // write private partial slice: [kb][o][tb]; D-frag col(tb)=xl, row(o)=q*4+reg
#pragma unroll
  for (int mt = 0; mt < 2; ++mt)
#pragma unroll
    for (int nt = 0; nt < 4; ++nt)
#pragma unroll
      for (int reg = 0; reg < 4; ++reg) {
        int o = m0 + mt * 16 + q * 4 + reg;
        partial[((size_t)kb * 256 + o) * 1024 + n0 + nt * 16 + xl] = acc[mt][nt][reg];
      }
}

// ---- reduce partials (sum over kb) + LIF -> fc1 spikes [t][b][o]. ----
__global__ __launch_bounds__(256) void reduce_lif(const float* __restrict__ partial, float* __restrict__ fs) {
  int idx = blockIdx.x * 256 + threadIdx.x;   // 32768 = o*128 + b
  int o = idx >> 7, b = idx & 127;
  float v = 0.f;
#pragma unroll 1
  for (int t = 0; t < 8; ++t) {
    float xv = 0.f;
#pragma unroll
    for (int kb = 0; kb < 16; ++kb)
      xv += partial[((size_t)kb * 256 + o) * 1024 + t * 128 + b];
    float s;
    LIF_STEP(v, xv, s);
    fs[t * 32768 + b * 256 + o] = s;
  }
}

__global__ __launch_bounds__(256) void fc2_kernel(const float* __restrict__ fs, const float* __restrict__ w,
                                                  const float* __restrict__ bias, float* __restrict__ outp) {
  int tb = blockIdx.x;
  __shared__ float sv[256];
  int tid = threadIdx.x;
  sv[tid] = fs[tb * 256 + tid];
  __syncthreads();
  if (tid < 10) {
    float a = bias[tid];
    const float* wr = w + tid * 256;
#pragma unroll 8
    for (int o = 0; o < 256; ++o) a = fmaf(sv[o], wr[o], a);
    outp[tb * 10 + tid] = a;
  }
}

extern "C" void kernel_launch(void* const* d_in, const int* in_sizes, int n_in,
                              void* d_out, int out_size, void* d_ws, size_t ws_size,
                              hipStream_t stream) {
  (void)in_sizes; (void)n_in; (void)out_size; (void)ws_size;
  const float* x_seq   = (const float*)d_in[0];
  const float* conv1_w = (const float*)d_in[1];
  const float* bn1_g   = (const float*)d_in[2];
  const float* bn1_b   = (const float*)d_in[3];
  const float* conv2_w = (const float*)d_in[4];
  const float* bn2_g   = (const float*)d_in[5];
  const float* bn2_b   = (const float*)d_in[6];
  const float* fc1_w   = (const float*)d_in[7];
  const float* fc2_w   = (const float*)d_in[8];
  const float* fc2_b   = (const float*)d_in[9];
  float* out = (float*)d_out;
  float* ws  = (float*)d_ws;

  unsigned short* pool1 = (unsigned short*)(ws + OFF_POOL1);
  float* fc1_part = ws + OFF_POOL1;                     // reuses pool1 region post-conv2
  unsigned short* pool2 = (unsigned short*)(ws + OFF_POOL2);
  float* fc1_s   = ws + OFF_FC1S;
  unsigned short* A2 = (unsigned short*)(ws + OFF_A2);
  unsigned short* B1 = (unsigned short*)(ws + OFF_B1);
  float* st      = ws + OFF_STATS;
  float* s1_sum = st;        float* s1_sq  = st + 64;
  float* bn1_sc = st + 128;  float* bn1_sh = st + 192;
  float* s2_sum = st + 256;  float* s2_sq  = st + 384;
  float* bn2_sc = st + 512;  float* bn2_sh = st + 640;

  // 1. zero stats (atomics target; ws is poisoned every call)
  zero_kernel<<<3, 256, 0, stream>>>(st, 768u);
  // 2. weight preps (bf16 3-way splits into MFMA frag layouts)
  prep_w2<<<288, 256, 0, stream>>>(conv2_w, A2);
  prep_b1<<<8192, 256, 0, stream>>>(fc1_w, B1);
  // 3. conv1 stats
  conv1_pass1<<<1024, 256, 0, stream>>>(x_seq, conv1_w, s1_sum, s1_sq);
  // 4. BN1 finalize
  finalize_bn<<<1, 64, 0, stream>>>(s1_sum, s1_sq, bn1_g, bn1_b, bn1_sc, bn1_sh, 1.0f / 1048576.0f);
  // 5. fused conv1+BN+LIF+pool -> pool1 (bf16)
  conv1_fused<<<1024, 256, 0, stream>>>(x_seq, conv1_w, bn1_sc, bn1_sh, pool1);
  // 6. conv2 stats via MFMA
  conv2_pass1_mfma<<<1024, 256, 0, stream>>>(pool1, A2, s2_sum, s2_sq);
  // 7. BN2 finalize
  finalize_bn<<<1, 128, 0, stream>>>(s2_sum, s2_sq, bn2_g, bn2_b, bn2_sc, bn2_sh, 1.0f / 262144.0f);
  // 8. fused conv2+BN+LIF+pool via MFMA -> pool2 [tb][ci][s]  (pool1 dead after this)
  conv2_fused_mfma<<<512, 256, 0, stream>>>(pool1, A2, bn2_sc, bn2_sh, pool2);
  // 9. fc1 MFMA split-K=16 -> private partials (pool1 region), no atomics
  fc1_mfma<<<512, 256, 0, stream>>>(pool2, B1, fc1_part);
  // 10. reduce partials + LIF -> fc1 spikes
  reduce_lif<<<128, 256, 0, stream>>>(fc1_part, fc1_s);
  // 11. fc2 + bias -> logits [8,128,10]
  fc2_kernel<<<1024, 256, 0, stream>>>(fc1_s, fc2_w, fc2_b, out);
}